// Round 9
// baseline (513.177 us; speedup 1.0000x reference)
//
#include <hip/hip_runtime.h>

#define N_NODES 50000
#define N_EDGES 800000
#define HDIM 128
#define ODIM 64
#define NLAYER 3
#define NGRAPH 512
#define BN_EPS 1e-5f
#define BCAP 48      // bucket capacity; deg ~ Poisson(16), P(deg>=48) ~ 1e-9/node
#define NBLK 782     // mlp2 grid: ceil(50000/64)
#define GBLK 1564    // gml grid: ceil(50000/32)
#define PBLK 1600    // partial-stats pitch (>= GBLK)
#define HPITCH 136   // LDS pitch for head t-tile
#define TPITCH 136   // LDS pitch for y/C tiles

// k_prep block-range partition
#define SCAT_BLK 782            // 800000 edges / 4 per thread / 256
#define CVT_BLK 6250            // 1.6M float4
#define CVTW_BLK 481            // 122880 weight elems + 256 sentinel zeros

typedef __attribute__((ext_vector_type(8))) short short8;
typedef __attribute__((ext_vector_type(8))) unsigned short ushort8;
typedef __attribute__((ext_vector_type(4))) float floatx4;

static __device__ __forceinline__ unsigned short f2bf(float f) {
    union { float f; unsigned int u; } v; v.f = f;
    unsigned int r = v.u + 0x7FFFu + ((v.u >> 16) & 1u);
    return (unsigned short)(r >> 16);
}
static __device__ __forceinline__ float bf2f(unsigned short s) {
    union { unsigned int u; float f; } v; v.u = ((unsigned int)s) << 16;
    return v.f;
}

// ---- fused prep: scatter (4 edges/thread) + cvt + cvtW + sentinel zero ----

__global__ __launch_bounds__(256) void k_prep(
    const int* __restrict__ src, const int* __restrict__ dst,
    int* __restrict__ cnt, unsigned short* __restrict__ colidx,
    const float* __restrict__ x, unsigned short* __restrict__ xb,
    const float* __restrict__ W1, const float* __restrict__ W2,
    const float* __restrict__ hW1, const float* __restrict__ hW2,
    unsigned short* __restrict__ wtb, unsigned short* __restrict__ xa2)
{
    int b = blockIdx.x;
    int tid = threadIdx.x;
    if (b < SCAT_BLK) {
        int base = (b * 256 + tid) * 4;
        if (base < N_EDGES) {
            int4 s4 = *(const int4*)(src + base);
            int4 d4 = *(const int4*)(dst + base);
            int p0 = atomicAdd(&cnt[d4.x], 1);
            int p1 = atomicAdd(&cnt[d4.y], 1);
            int p2 = atomicAdd(&cnt[d4.z], 1);
            int p3 = atomicAdd(&cnt[d4.w], 1);
            if (p0 < BCAP) colidx[d4.x * BCAP + p0] = (unsigned short)s4.x;
            if (p1 < BCAP) colidx[d4.y * BCAP + p1] = (unsigned short)s4.y;
            if (p2 < BCAP) colidx[d4.z * BCAP + p2] = (unsigned short)s4.z;
            if (p3 < BCAP) colidx[d4.w * BCAP + p3] = (unsigned short)s4.w;
        }
    } else if (b < SCAT_BLK + CVT_BLK) {
        int i = (b - SCAT_BLK) * 256 + tid;
        if (i < N_NODES * HDIM / 4) {
            float4 v = ((const float4*)x)[i];
            ushort4 o = make_ushort4(f2bf(v.x), f2bf(v.y), f2bf(v.z), f2bf(v.w));
            ((ushort4*)xb)[i] = o;
        }
    } else {
        int idx = (b - SCAT_BLK - CVT_BLK) * 256 + tid;
        if (idx < 6 * HDIM * HDIM) {
            // conv weights: mat 2l=W1[l], 2l+1=W2[l]; [k][n] -> [n][k] bf16
            int mat = idx >> 14;
            int rem = idx & 16383;
            int k = rem >> 7, n = rem & 127;
            int l = mat >> 1;
            const float* W = (mat & 1) ? (W2 + l * HDIM * HDIM) : (W1 + l * HDIM * HDIM);
            wtb[mat * HDIM * HDIM + n * HDIM + k] = f2bf(W[k * HDIM + n]);
        } else if (idx < 7 * HDIM * HDIM) {
            int j = idx - 6 * HDIM * HDIM;
            int n = j >> 7, k = j & 127;
            wtb[idx] = f2bf(hW1[k * HDIM + n]);
        } else if (idx < 7 * HDIM * HDIM + ODIM * HDIM) {
            int j = idx - 7 * HDIM * HDIM;
            int n = j >> 7, k = j & 127;   // n in [0,64)
            wtb[idx] = f2bf(hW2[k * ODIM + n]);
        } else if (idx < 7 * HDIM * HDIM + ODIM * HDIM + HDIM) {
            xb[(size_t)N_NODES * HDIM + (idx - 7 * HDIM * HDIM - ODIM * HDIM)] = 0;
        } else if (idx < 7 * HDIM * HDIM + ODIM * HDIM + 2 * HDIM) {
            xa2[(size_t)N_NODES * HDIM + (idx - 7 * HDIM * HDIM - ODIM * HDIM - HDIM)] = 0;
        }
    }
}

// pad each bucket to a multiple of 8 with sentinel row N_NODES (zero row)
__global__ __launch_bounds__(256) void k_pad(const int* __restrict__ cnt,
                                             unsigned short* __restrict__ colidx) {
    int n = blockIdx.x * 256 + threadIdx.x;
    if (n < N_NODES) {
        int d = cnt[n]; if (d > BCAP) d = BCAP;
        int end = (d + 7) & ~7;
        for (int i = d; i < end; ++i) colidx[n * BCAP + i] = (unsigned short)N_NODES;
    }
}

// ---- fused gather + mlp1: y=x+sum(neigh) in LDS, h=y@W1+b1, BN partials ----
// 512 threads, 32 nodes/block -> exactly one gather task per thread.
// Edge loop unrolled x16 (16 row loads in flight). MFMA: 8 waves, 16r x 32c each.

__global__ __launch_bounds__(512, 6) void k_gml(
    const unsigned short* __restrict__ x,
    const int* __restrict__ cnt,
    const unsigned short* __restrict__ colidx,
    const unsigned short* __restrict__ wt,   // [n][k] bf16
    const float* __restrict__ b1,
    unsigned short* __restrict__ hout,
    float* __restrict__ pout)                // [256][PBLK] partials
{
    __shared__ float s_sum[HDIM], s_sq[HDIM];
    __shared__ __align__(16) unsigned short yb[32 * TPITCH];
    int tid = threadIdx.x;
    if (tid < HDIM) { s_sum[tid] = 0.f; s_sq[tid] = 0.f; }
    int nbase = blockIdx.x * 32;

    // ---- gather into LDS: one (node, 16B-seg) task per thread ----
    {
        int nl = tid >> 4;
        int seg = (tid & 15) * 8;
        int gnode = nbase + nl;
        float acc[8] = {0.f, 0.f, 0.f, 0.f, 0.f, 0.f, 0.f, 0.f};
        if (gnode < N_NODES) {
            short8 v = *(const short8*)(x + (size_t)gnode * HDIM + seg);
#pragma unroll
            for (int j = 0; j < 8; ++j) acc[j] = bf2f((unsigned short)v[j]);
            int deg = cnt[gnode]; if (deg > BCAP) deg = BCAP;
            int e = gnode * BCAP;
            int end = e + ((deg + 7) & ~7);
            for (; e + 16 <= end; e += 16) {
                ushort8 i0 = *(const ushort8*)(colidx + e);
                ushort8 i1 = *(const ushort8*)(colidx + e + 8);
                short8 v0 = *(const short8*)(x + (size_t)i0[0] * HDIM + seg);
                short8 v1 = *(const short8*)(x + (size_t)i0[1] * HDIM + seg);
                short8 v2 = *(const short8*)(x + (size_t)i0[2] * HDIM + seg);
                short8 v3 = *(const short8*)(x + (size_t)i0[3] * HDIM + seg);
                short8 v4 = *(const short8*)(x + (size_t)i0[4] * HDIM + seg);
                short8 v5 = *(const short8*)(x + (size_t)i0[5] * HDIM + seg);
                short8 v6 = *(const short8*)(x + (size_t)i0[6] * HDIM + seg);
                short8 v7 = *(const short8*)(x + (size_t)i0[7] * HDIM + seg);
                short8 w0 = *(const short8*)(x + (size_t)i1[0] * HDIM + seg);
                short8 w1 = *(const short8*)(x + (size_t)i1[1] * HDIM + seg);
                short8 w2 = *(const short8*)(x + (size_t)i1[2] * HDIM + seg);
                short8 w3 = *(const short8*)(x + (size_t)i1[3] * HDIM + seg);
                short8 w4 = *(const short8*)(x + (size_t)i1[4] * HDIM + seg);
                short8 w5 = *(const short8*)(x + (size_t)i1[5] * HDIM + seg);
                short8 w6 = *(const short8*)(x + (size_t)i1[6] * HDIM + seg);
                short8 w7 = *(const short8*)(x + (size_t)i1[7] * HDIM + seg);
#pragma unroll
                for (int j = 0; j < 8; ++j) {
                    float a = (bf2f((unsigned short)v0[j]) + bf2f((unsigned short)v1[j])) +
                              (bf2f((unsigned short)v2[j]) + bf2f((unsigned short)v3[j]));
                    float bq = (bf2f((unsigned short)v4[j]) + bf2f((unsigned short)v5[j])) +
                               (bf2f((unsigned short)v6[j]) + bf2f((unsigned short)v7[j]));
                    float c = (bf2f((unsigned short)w0[j]) + bf2f((unsigned short)w1[j])) +
                              (bf2f((unsigned short)w2[j]) + bf2f((unsigned short)w3[j]));
                    float d = (bf2f((unsigned short)w4[j]) + bf2f((unsigned short)w5[j])) +
                              (bf2f((unsigned short)w6[j]) + bf2f((unsigned short)w7[j]));
                    acc[j] += (a + bq) + (c + d);
                }
            }
            for (; e < end; e += 8) {
                ushort8 i0 = *(const ushort8*)(colidx + e);
                short8 v0 = *(const short8*)(x + (size_t)i0[0] * HDIM + seg);
                short8 v1 = *(const short8*)(x + (size_t)i0[1] * HDIM + seg);
                short8 v2 = *(const short8*)(x + (size_t)i0[2] * HDIM + seg);
                short8 v3 = *(const short8*)(x + (size_t)i0[3] * HDIM + seg);
                short8 v4 = *(const short8*)(x + (size_t)i0[4] * HDIM + seg);
                short8 v5 = *(const short8*)(x + (size_t)i0[5] * HDIM + seg);
                short8 v6 = *(const short8*)(x + (size_t)i0[6] * HDIM + seg);
                short8 v7 = *(const short8*)(x + (size_t)i0[7] * HDIM + seg);
#pragma unroll
                for (int j = 0; j < 8; ++j)
                    acc[j] += ((bf2f((unsigned short)v0[j]) + bf2f((unsigned short)v1[j])) +
                               (bf2f((unsigned short)v2[j]) + bf2f((unsigned short)v3[j]))) +
                              ((bf2f((unsigned short)v4[j]) + bf2f((unsigned short)v5[j])) +
                               (bf2f((unsigned short)v6[j]) + bf2f((unsigned short)v7[j])));
            }
        }
        short8 o;
#pragma unroll
        for (int j = 0; j < 8; ++j) o[j] = (short)f2bf(acc[j]);
        *(short8*)&yb[(tid >> 4) * TPITCH + seg] = o;
    }
    __syncthreads();

    // ---- MFMA: h = y @ W1; wave w -> rows (w&1)*16.., cols (w>>1)*32.. ----
    int wv = tid >> 6, lane = tid & 63;
    int m = lane & 15, quad = lane >> 4;
    int r0 = (wv & 1) * 16;
    int c0 = (wv >> 1) * 32;

    short8 a[4];
#pragma unroll
    for (int kk = 0; kk < 4; ++kk)
        a[kk] = *(const short8*)&yb[(r0 + m) * TPITCH + kk * 32 + quad * 8];
    __syncthreads();   // all A-frag reads complete before C overwrites yb

    floatx4 acc2[2];
#pragma unroll
    for (int nt = 0; nt < 2; ++nt) {
        floatx4 c = {0.f, 0.f, 0.f, 0.f};
#pragma unroll
        for (int kk = 0; kk < 4; ++kk) {
            short8 b = *(const short8*)(wt + (c0 + nt * 16 + m) * HDIM + kk * 32 + quad * 8);
            c = __builtin_amdgcn_mfma_f32_16x16x32_bf16(a[kk], b, c, 0, 0, 0);
        }
        acc2[nt] = c;
    }

    // epilogue: +b1, stats, C -> LDS
    int lrow0 = r0 + quad * 4;
#pragma unroll
    for (int nt = 0; nt < 2; ++nt) {
        int n = c0 + nt * 16 + m;
        float bias = b1[n];
        float ssum = 0.f, ssq = 0.f;
#pragma unroll
        for (int r = 0; r < 4; ++r) {
            float val = acc2[nt][r] + bias;
            yb[(lrow0 + r) * TPITCH + n] = f2bf(val);
            if (nbase + lrow0 + r < N_NODES) { ssum += val; ssq += val * val; }
        }
        atomicAdd(&s_sum[n], ssum);
        atomicAdd(&s_sq[n], ssq);
    }
    __syncthreads();
    if (tid < HDIM) {
        pout[(size_t)tid * PBLK + blockIdx.x] = s_sum[tid];
        pout[(size_t)(tid + HDIM) * PBLK + blockIdx.x] = s_sq[tid];
    }
    // coalesced store: 16 threads/row, 16 B each
    int lrow = tid >> 4, off = (tid & 15) * 8;
    int grow = nbase + lrow;
    if (grow < N_NODES)
        *(short8*)(hout + (size_t)grow * HDIM + off) = *(const short8*)&yb[lrow * TPITCH + off];
}

// ---------------- stats: reduce partials, one block per column ----------------

__global__ __launch_bounds__(256) void k_stats(const float* __restrict__ p,
                                               float* __restrict__ stats) {
    int c = blockIdx.x;          // 0..255 (128 sum + 128 sumsq)
    int tid = threadIdx.x;
    const float* col = p + (size_t)c * PBLK;
    float s = 0.f;
    for (int i = tid; i < GBLK; i += 256) s += col[i];
#pragma unroll
    for (int off = 32; off; off >>= 1) s += __shfl_down(s, off, 64);
    __shared__ float red[4];
    if ((tid & 63) == 0) red[tid >> 6] = s;
    __syncthreads();
    if (tid == 0) stats[c] = red[0] + red[1] + red[2] + red[3];
}

// ------- mlp2: x' = relu(BN(h) relu'd @ W2 + b2); LDS-staged C store -------

__global__ __launch_bounds__(256) void k_mlp2(
    const unsigned short* __restrict__ hin,
    const float* __restrict__ stats,
    const float* __restrict__ gamma,
    const float* __restrict__ beta,
    const unsigned short* __restrict__ wt,   // [n][k] bf16
    const float* __restrict__ b2,
    unsigned short* __restrict__ xout)
{
    __shared__ float s_scale[HDIM], s_shift[HDIM];
    __shared__ __align__(16) unsigned short tb[64 * TPITCH];
    int tid = threadIdx.x;
    if (tid < HDIM) {
        float mu = stats[tid] * (1.f / N_NODES);
        float var = stats[HDIM + tid] * (1.f / N_NODES) - mu * mu;
        float sc = gamma[tid] * rsqrtf(var + BN_EPS);
        s_scale[tid] = sc;
        s_shift[tid] = beta[tid] - mu * sc;
    }
    __syncthreads();

    int wv = tid >> 6, lane = tid & 63;
    int m = lane & 15, quad = lane >> 4;
    int row0 = blockIdx.x * 64 + wv * 16;
    int arow = row0 + m;

    short8 a[4];
    if (arow < N_NODES) {
#pragma unroll
        for (int kk = 0; kk < 4; ++kk) {
            short8 v = *(const short8*)(hin + (size_t)arow * HDIM + kk * 32 + quad * 8);
            int c0 = kk * 32 + quad * 8;
            short8 af;
#pragma unroll
            for (int j = 0; j < 8; ++j) {
                float f = fmaxf(bf2f((unsigned short)v[j]) * s_scale[c0 + j] + s_shift[c0 + j], 0.f);
                af[j] = (short)f2bf(f);
            }
            a[kk] = af;
        }
    } else {
#pragma unroll
        for (int kk = 0; kk < 4; ++kk) a[kk] = (short8)0;
    }

    floatx4 acc[8];
#pragma unroll
    for (int nt = 0; nt < 8; ++nt) {
        floatx4 c = {0.f, 0.f, 0.f, 0.f};
#pragma unroll
        for (int kk = 0; kk < 4; ++kk) {
            short8 b = *(const short8*)(wt + (nt * 16 + m) * HDIM + kk * 32 + quad * 8);
            c = __builtin_amdgcn_mfma_f32_16x16x32_bf16(a[kk], b, c, 0, 0, 0);
        }
        acc[nt] = c;
    }

    int lrow0 = wv * 16 + quad * 4;
#pragma unroll
    for (int nt = 0; nt < 8; ++nt) {
        int n = nt * 16 + m;
        float bias = b2[n];
#pragma unroll
        for (int r = 0; r < 4; ++r)
            tb[(lrow0 + r) * TPITCH + n] = f2bf(fmaxf(acc[nt][r] + bias, 0.f));
    }
    __syncthreads();
    int lrow = tid >> 2, off = (tid & 3) * 32;
    int grow = blockIdx.x * 64 + lrow;
    if (grow < N_NODES) {
#pragma unroll
        for (int i = 0; i < 4; ++i)
            *(short8*)(xout + (size_t)grow * HDIM + off + i * 8) =
                *(const short8*)&tb[lrow * TPITCH + off + i * 8];
    }
}

// ---------------- pool: g[gid] = sum of node rows (bf16 out) ----------------

__global__ __launch_bounds__(256) void k_pool(
    const unsigned short* __restrict__ xf,
    const int* __restrict__ batch,
    unsigned short* __restrict__ g)
{
    __shared__ float red[16][HDIM];
    int gid = blockIdx.x;
    int tid = threadIdx.x;

    int lo = 0, hi = N_NODES;
    while (lo < hi) { int mid = (lo + hi) >> 1; if (batch[mid] < gid) lo = mid + 1; else hi = mid; }
    int start = lo;
    int lo2 = start, hi2 = N_NODES;
    while (lo2 < hi2) { int mid = (lo2 + hi2) >> 1; if (batch[mid] < gid + 1) lo2 = mid + 1; else hi2 = mid; }
    int end = lo2;

    int tsub = tid & 15, rgrp = tid >> 4;
    int seg = tsub * 8;
    float acc[8] = {0.f, 0.f, 0.f, 0.f, 0.f, 0.f, 0.f, 0.f};
    for (int r = start + rgrp; r < end; r += 16) {
        short8 v = *(const short8*)(xf + (size_t)r * HDIM + seg);
#pragma unroll
        for (int j = 0; j < 8; ++j) acc[j] += bf2f((unsigned short)v[j]);
    }
#pragma unroll
    for (int j = 0; j < 8; ++j) red[rgrp][seg + j] = acc[j];
    __syncthreads();
    if (tid < HDIM) {
        float s = 0.f;
#pragma unroll
        for (int i = 0; i < 16; ++i) s += red[i][tid];
        g[gid * HDIM + tid] = f2bf(s);
    }
}

// ---------------- head: out = relu(g@hW1+b1) @ hW2 + b2 (block-local) -------

__global__ __launch_bounds__(256) void k_head(
    const unsigned short* __restrict__ g,
    const unsigned short* __restrict__ w1t,  // [128][128] bf16 [n][k]
    const float* __restrict__ b1,
    const unsigned short* __restrict__ w2t,  // [64][128] bf16 [n][k]
    const float* __restrict__ b2,
    float* __restrict__ out)
{
    __shared__ unsigned short tb[64 * HPITCH];
    int tid = threadIdx.x;
    int wv = tid >> 6, lane = tid & 63;
    int m = lane & 15, quad = lane >> 4;
    int row0 = blockIdx.x * 64 + wv * 16;

    short8 a[4];
#pragma unroll
    for (int kk = 0; kk < 4; ++kk)
        a[kk] = *(const short8*)(g + (size_t)(row0 + m) * HDIM + kk * 32 + quad * 8);

    // stage 1: t = relu(g @ W1 + b1), 64x128, staged to LDS
#pragma unroll
    for (int nt = 0; nt < 8; ++nt) {
        floatx4 c = {0.f, 0.f, 0.f, 0.f};
#pragma unroll
        for (int kk = 0; kk < 4; ++kk) {
            short8 b = *(const short8*)(w1t + (nt * 16 + m) * HDIM + kk * 32 + quad * 8);
            c = __builtin_amdgcn_mfma_f32_16x16x32_bf16(a[kk], b, c, 0, 0, 0);
        }
        int n = nt * 16 + m;
        float bias = b1[n];
#pragma unroll
        for (int r = 0; r < 4; ++r) {
            int lrow = wv * 16 + quad * 4 + r;
            tb[lrow * HPITCH + n] = f2bf(fmaxf(c[r] + bias, 0.f));
        }
    }
    __syncthreads();

    // stage 2: out = t @ W2 + b2, 64x64
    short8 a2[4];
#pragma unroll
    for (int kk = 0; kk < 4; ++kk)
        a2[kk] = *(const short8*)&tb[(wv * 16 + m) * HPITCH + kk * 32 + quad * 8];

#pragma unroll
    for (int nt = 0; nt < 4; ++nt) {
        floatx4 c = {0.f, 0.f, 0.f, 0.f};
#pragma unroll
        for (int kk = 0; kk < 4; ++kk) {
            short8 b = *(const short8*)(w2t + (nt * 16 + m) * HDIM + kk * 32 + quad * 8);
            c = __builtin_amdgcn_mfma_f32_16x16x32_bf16(a2[kk], b, c, 0, 0, 0);
        }
        int n = nt * 16 + m;
        float bias = b2[n];
#pragma unroll
        for (int r = 0; r < 4; ++r) {
            int row = row0 + quad * 4 + r;
            out[(size_t)row * ODIM + n] = c[r] + bias;
        }
    }
}

// ---------------- launch ----------------

extern "C" void kernel_launch(void* const* d_in, const int* in_sizes, int n_in,
                              void* d_out, int out_size, void* d_ws, size_t ws_size,
                              hipStream_t stream) {
    const float* x        = (const float*)d_in[0];
    const float* conv_W1  = (const float*)d_in[1];
    const float* conv_b1  = (const float*)d_in[2];
    const float* conv_g   = (const float*)d_in[3];
    const float* conv_be  = (const float*)d_in[4];
    const float* conv_W2  = (const float*)d_in[5];
    const float* conv_b2  = (const float*)d_in[6];
    const float* head_W1  = (const float*)d_in[7];
    const float* head_b1  = (const float*)d_in[8];
    const float* head_W2  = (const float*)d_in[9];
    const float* head_b2  = (const float*)d_in[10];
    const int*   edges    = (const int*)d_in[11];   // [0..E)=src, [E..2E)=dst
    const int*   batch    = (const int*)d_in[12];

    char* ws = (char*)d_ws;
    int*            cnt    = (int*)(ws + 0);                    // 200,000 B
    float*          stats  = (float*)(ws + 200000);             // 3*256*4 = 3,072 B
    unsigned short* colidx = (unsigned short*)(ws + 203072);    // 50000*48*2 = 4,800,000 B
    unsigned short* wtb    = (unsigned short*)(ws + 5003072);   // 245,760 B
    float*          part   = (float*)(ws + 5248832);            // 256*1600*4 = 1,638,400 B
    unsigned short* gbuf   = (unsigned short*)(ws + 6887232);   // 131,072 B
    unsigned short* xa     = (unsigned short*)(ws + 7018304);   // (N+1) rows = 12,800,256 B
    unsigned short* xb     = (unsigned short*)(ws + 19818560);  // 12,800,256 B
    (void)in_sizes; (void)n_in; (void)out_size; (void)ws_size;

    hipMemsetAsync(ws, 0, 200000, stream);                      // cnt only

    k_prep<<<SCAT_BLK + CVT_BLK + CVTW_BLK, 256, 0, stream>>>(
        edges, edges + N_EDGES, cnt, colidx, x, xa,
        conv_W1, conv_W2, head_W1, head_W2, wtb, xb);
    k_pad<<<(N_NODES + 255) / 256, 256, 0, stream>>>(cnt, colidx);

    // x lives in xa for every layer; h in xb.
    for (int l = 0; l < NLAYER; ++l) {
        k_gml<<<GBLK, 512, 0, stream>>>(xa, cnt, colidx,
                                        wtb + (2 * l) * HDIM * HDIM,
                                        conv_b1 + l * HDIM, xb, part);
        k_stats<<<256, 256, 0, stream>>>(part, stats + l * 256);
        k_mlp2<<<NBLK, 256, 0, stream>>>(xb, stats + l * 256,
                                         conv_g + l * HDIM, conv_be + l * HDIM,
                                         wtb + (2 * l + 1) * HDIM * HDIM,
                                         conv_b2 + l * HDIM, xa);
    }

    k_pool<<<NGRAPH, 256, 0, stream>>>(xa, batch, gbuf);
    k_head<<<NGRAPH / 64, 256, 0, stream>>>(gbuf, wtb + 6 * HDIM * HDIM, head_b1,
                                            wtb + 7 * HDIM * HDIM, head_b2,
                                            (float*)d_out);
}

// Round 10
// 433.127 us; speedup vs baseline: 1.1848x; 1.1848x over previous
//
#include <hip/hip_runtime.h>

#define N_NODES 50000
#define N_EDGES 800000
#define HDIM 128
#define ODIM 64
#define NLAYER 3
#define NGRAPH 512
#define BN_EPS 1e-5f
#define BCAP 48      // bucket capacity; deg ~ Poisson(16), P(deg>=48) ~ 1e-9/node
#define NBLK 782     // mlp grid: ceil(50000/64)
#define GBLK 782     // gml grid: ceil(50000/64)
#define HPITCH 136   // LDS pitch for head t-tile
#define TPITCH 136   // LDS pitch for y/C tiles

// k_prep block-range partition
#define SCAT_BLK 782            // 800000 edges / 4 per thread / 256
#define CVT_BLK 6250            // 1.6M float4
#define CVTW_BLK 481            // 122880 weight elems + 256 sentinel zeros

typedef __attribute__((ext_vector_type(8))) short short8;
typedef __attribute__((ext_vector_type(8))) unsigned short ushort8;
typedef __attribute__((ext_vector_type(4))) float floatx4;

static __device__ __forceinline__ unsigned short f2bf(float f) {
    union { float f; unsigned int u; } v; v.f = f;
    unsigned int r = v.u + 0x7FFFu + ((v.u >> 16) & 1u);
    return (unsigned short)(r >> 16);
}
static __device__ __forceinline__ float bf2f(unsigned short s) {
    union { unsigned int u; float f; } v; v.u = ((unsigned int)s) << 16;
    return v.f;
}

// ---- fused prep: scatter (4 edges/thread) + cvt + cvtW + sentinel zero ----

__global__ __launch_bounds__(256) void k_prep(
    const int* __restrict__ src, const int* __restrict__ dst,
    int* __restrict__ cnt, unsigned short* __restrict__ colidx,
    const float* __restrict__ x, unsigned short* __restrict__ xb,
    const float* __restrict__ W1, const float* __restrict__ W2,
    const float* __restrict__ hW1, const float* __restrict__ hW2,
    unsigned short* __restrict__ wtb, unsigned short* __restrict__ xa2)
{
    int b = blockIdx.x;
    int tid = threadIdx.x;
    if (b < SCAT_BLK) {
        int base = (b * 256 + tid) * 4;
        if (base < N_EDGES) {
            int4 s4 = *(const int4*)(src + base);
            int4 d4 = *(const int4*)(dst + base);
            int p0 = atomicAdd(&cnt[d4.x], 1);
            int p1 = atomicAdd(&cnt[d4.y], 1);
            int p2 = atomicAdd(&cnt[d4.z], 1);
            int p3 = atomicAdd(&cnt[d4.w], 1);
            if (p0 < BCAP) colidx[d4.x * BCAP + p0] = (unsigned short)s4.x;
            if (p1 < BCAP) colidx[d4.y * BCAP + p1] = (unsigned short)s4.y;
            if (p2 < BCAP) colidx[d4.z * BCAP + p2] = (unsigned short)s4.z;
            if (p3 < BCAP) colidx[d4.w * BCAP + p3] = (unsigned short)s4.w;
        }
    } else if (b < SCAT_BLK + CVT_BLK) {
        int i = (b - SCAT_BLK) * 256 + tid;
        if (i < N_NODES * HDIM / 4) {
            float4 v = ((const float4*)x)[i];
            ushort4 o = make_ushort4(f2bf(v.x), f2bf(v.y), f2bf(v.z), f2bf(v.w));
            ((ushort4*)xb)[i] = o;
        }
    } else {
        int idx = (b - SCAT_BLK - CVT_BLK) * 256 + tid;
        if (idx < 6 * HDIM * HDIM) {
            // conv weights: mat 2l=W1[l], 2l+1=W2[l]; [k][n] -> [n][k] bf16
            int mat = idx >> 14;
            int rem = idx & 16383;
            int k = rem >> 7, n = rem & 127;
            int l = mat >> 1;
            const float* W = (mat & 1) ? (W2 + l * HDIM * HDIM) : (W1 + l * HDIM * HDIM);
            wtb[mat * HDIM * HDIM + n * HDIM + k] = f2bf(W[k * HDIM + n]);
        } else if (idx < 7 * HDIM * HDIM) {
            int j = idx - 6 * HDIM * HDIM;
            int n = j >> 7, k = j & 127;
            wtb[idx] = f2bf(hW1[k * HDIM + n]);
        } else if (idx < 7 * HDIM * HDIM + ODIM * HDIM) {
            int j = idx - 7 * HDIM * HDIM;
            int n = j >> 7, k = j & 127;   // n in [0,64)
            wtb[idx] = f2bf(hW2[k * ODIM + n]);
        } else if (idx < 7 * HDIM * HDIM + ODIM * HDIM + HDIM) {
            xb[(size_t)N_NODES * HDIM + (idx - 7 * HDIM * HDIM - ODIM * HDIM)] = 0;
        } else if (idx < 7 * HDIM * HDIM + ODIM * HDIM + 2 * HDIM) {
            xa2[(size_t)N_NODES * HDIM + (idx - 7 * HDIM * HDIM - ODIM * HDIM - HDIM)] = 0;
        }
    }
}

// pad each bucket to a multiple of 8 with sentinel row N_NODES (zero row)
__global__ __launch_bounds__(256) void k_pad(const int* __restrict__ cnt,
                                             unsigned short* __restrict__ colidx) {
    int n = blockIdx.x * 256 + threadIdx.x;
    if (n < N_NODES) {
        int d = cnt[n]; if (d > BCAP) d = BCAP;
        int end = (d + 7) & ~7;
        for (int i = d; i < end; ++i) colidx[n * BCAP + i] = (unsigned short)N_NODES;
    }
}

// ---- fused gather + mlp1 (R8-proven shape): 64 nodes/block, 512 threads ----
// Phase1: 1024 gather tasks (node,16B-seg), 2 sequential per thread, unroll-8.
// Phase2: 8 waves, wave w -> rows (w&3)*16.., cols (w>>2)*64..; LDS tile reused.

__global__ __launch_bounds__(512, 6) void k_gml(
    const unsigned short* __restrict__ x,
    const int* __restrict__ cnt,
    const unsigned short* __restrict__ colidx,
    const unsigned short* __restrict__ wt,   // [n][k] bf16
    const float* __restrict__ b1,
    unsigned short* __restrict__ hout,
    float* __restrict__ pout)                // [GBLK][256] contiguous partials
{
    __shared__ float s_sum[HDIM], s_sq[HDIM];
    __shared__ __align__(16) unsigned short yb[64 * TPITCH];
    int tid = threadIdx.x;
    if (tid < HDIM) { s_sum[tid] = 0.f; s_sq[tid] = 0.f; }
    int nbase = blockIdx.x * 64;

    // ---- gather into LDS ----
#pragma unroll
    for (int t = tid; t < 1024; t += 512) {
        int nl = t >> 4;
        int seg = (t & 15) * 8;
        int gnode = nbase + nl;
        float acc[8] = {0.f, 0.f, 0.f, 0.f, 0.f, 0.f, 0.f, 0.f};
        if (gnode < N_NODES) {
            short8 v = *(const short8*)(x + (size_t)gnode * HDIM + seg);
#pragma unroll
            for (int j = 0; j < 8; ++j) acc[j] = bf2f((unsigned short)v[j]);
            int deg = cnt[gnode]; if (deg > BCAP) deg = BCAP;
            int e = gnode * BCAP;
            int end = e + ((deg + 7) & ~7);
            for (; e < end; e += 8) {
                ushort8 i0 = *(const ushort8*)(colidx + e);
                short8 v0 = *(const short8*)(x + (size_t)i0[0] * HDIM + seg);
                short8 v1 = *(const short8*)(x + (size_t)i0[1] * HDIM + seg);
                short8 v2 = *(const short8*)(x + (size_t)i0[2] * HDIM + seg);
                short8 v3 = *(const short8*)(x + (size_t)i0[3] * HDIM + seg);
                short8 v4 = *(const short8*)(x + (size_t)i0[4] * HDIM + seg);
                short8 v5 = *(const short8*)(x + (size_t)i0[5] * HDIM + seg);
                short8 v6 = *(const short8*)(x + (size_t)i0[6] * HDIM + seg);
                short8 v7 = *(const short8*)(x + (size_t)i0[7] * HDIM + seg);
#pragma unroll
                for (int j = 0; j < 8; ++j)
                    acc[j] += ((bf2f((unsigned short)v0[j]) + bf2f((unsigned short)v1[j])) +
                               (bf2f((unsigned short)v2[j]) + bf2f((unsigned short)v3[j]))) +
                              ((bf2f((unsigned short)v4[j]) + bf2f((unsigned short)v5[j])) +
                               (bf2f((unsigned short)v6[j]) + bf2f((unsigned short)v7[j])));
            }
        }
        short8 o;
#pragma unroll
        for (int j = 0; j < 8; ++j) o[j] = (short)f2bf(acc[j]);
        *(short8*)&yb[nl * TPITCH + seg] = o;
    }
    __syncthreads();

    // ---- MFMA: h = y @ W1 ----
    int wv = tid >> 6, lane = tid & 63;
    int m = lane & 15, quad = lane >> 4;
    int mrow = (wv & 3) * 16 + m;
    int ncol0 = (wv >> 2) * 64;

    short8 a[4];
#pragma unroll
    for (int kk = 0; kk < 4; ++kk)
        a[kk] = *(const short8*)&yb[mrow * TPITCH + kk * 32 + quad * 8];
    __syncthreads();   // all A-frag reads complete before C overwrites yb

    floatx4 acc4[4];
#pragma unroll
    for (int nt = 0; nt < 4; ++nt) {
        floatx4 c = {0.f, 0.f, 0.f, 0.f};
#pragma unroll
        for (int kk = 0; kk < 4; ++kk) {
            short8 b = *(const short8*)(wt + (ncol0 + nt * 16 + m) * HDIM + kk * 32 + quad * 8);
            c = __builtin_amdgcn_mfma_f32_16x16x32_bf16(a[kk], b, c, 0, 0, 0);
        }
        acc4[nt] = c;
    }

    // epilogue: +b1, stats, C -> LDS
    int lrow0 = (wv & 3) * 16 + quad * 4;
#pragma unroll
    for (int nt = 0; nt < 4; ++nt) {
        int n = ncol0 + nt * 16 + m;
        float bias = b1[n];
        float ssum = 0.f, ssq = 0.f;
#pragma unroll
        for (int r = 0; r < 4; ++r) {
            float val = acc4[nt][r] + bias;
            yb[(lrow0 + r) * TPITCH + n] = f2bf(val);
            if (nbase + lrow0 + r < N_NODES) { ssum += val; ssq += val * val; }
        }
        atomicAdd(&s_sum[n], ssum);
        atomicAdd(&s_sq[n], ssq);
    }
    __syncthreads();
    if (tid < HDIM) {
        // contiguous 1KB-per-block partials (no scattered write-allocate)
        pout[(size_t)blockIdx.x * 256 + tid] = s_sum[tid];
        pout[(size_t)blockIdx.x * 256 + HDIM + tid] = s_sq[tid];
    }
    // coalesced store: 8 threads/row, 32 B each
    int lrow = tid >> 3, off = (tid & 7) * 16;
    int grow = nbase + lrow;
    if (grow < N_NODES) {
        *(short8*)(hout + (size_t)grow * HDIM + off) = *(const short8*)&yb[lrow * TPITCH + off];
        *(short8*)(hout + (size_t)grow * HDIM + off + 8) = *(const short8*)&yb[lrow * TPITCH + off + 8];
    }
}

// ------- stats: reduce [GBLK][256] partials, one block per column ------------

__global__ __launch_bounds__(256) void k_stats(const float* __restrict__ p,
                                               float* __restrict__ stats) {
    int c = blockIdx.x;          // 0..255 (128 sum + 128 sumsq)
    int tid = threadIdx.x;
    float s = 0.f;
    for (int i = tid; i < GBLK; i += 256) s += p[(size_t)i * 256 + c];
#pragma unroll
    for (int off = 32; off; off >>= 1) s += __shfl_down(s, off, 64);
    __shared__ float red[4];
    if ((tid & 63) == 0) red[tid >> 6] = s;
    __syncthreads();
    if (tid == 0) stats[c] = red[0] + red[1] + red[2] + red[3];
}

// ------- mlp2: x' = relu(BN(h) relu'd @ W2 + b2); LDS-staged C store -------

__global__ __launch_bounds__(256) void k_mlp2(
    const unsigned short* __restrict__ hin,
    const float* __restrict__ stats,
    const float* __restrict__ gamma,
    const float* __restrict__ beta,
    const unsigned short* __restrict__ wt,   // [n][k] bf16
    const float* __restrict__ b2,
    unsigned short* __restrict__ xout)
{
    __shared__ float s_scale[HDIM], s_shift[HDIM];
    __shared__ __align__(16) unsigned short tb[64 * TPITCH];
    int tid = threadIdx.x;
    if (tid < HDIM) {
        float mu = stats[tid] * (1.f / N_NODES);
        float var = stats[HDIM + tid] * (1.f / N_NODES) - mu * mu;
        float sc = gamma[tid] * rsqrtf(var + BN_EPS);
        s_scale[tid] = sc;
        s_shift[tid] = beta[tid] - mu * sc;
    }
    __syncthreads();

    int wv = tid >> 6, lane = tid & 63;
    int m = lane & 15, quad = lane >> 4;
    int row0 = blockIdx.x * 64 + wv * 16;
    int arow = row0 + m;

    short8 a[4];
    if (arow < N_NODES) {
#pragma unroll
        for (int kk = 0; kk < 4; ++kk) {
            short8 v = *(const short8*)(hin + (size_t)arow * HDIM + kk * 32 + quad * 8);
            int c0 = kk * 32 + quad * 8;
            short8 af;
#pragma unroll
            for (int j = 0; j < 8; ++j) {
                float f = fmaxf(bf2f((unsigned short)v[j]) * s_scale[c0 + j] + s_shift[c0 + j], 0.f);
                af[j] = (short)f2bf(f);
            }
            a[kk] = af;
        }
    } else {
#pragma unroll
        for (int kk = 0; kk < 4; ++kk) a[kk] = (short8)0;
    }

    floatx4 acc[8];
#pragma unroll
    for (int nt = 0; nt < 8; ++nt) {
        floatx4 c = {0.f, 0.f, 0.f, 0.f};
#pragma unroll
        for (int kk = 0; kk < 4; ++kk) {
            short8 b = *(const short8*)(wt + (nt * 16 + m) * HDIM + kk * 32 + quad * 8);
            c = __builtin_amdgcn_mfma_f32_16x16x32_bf16(a[kk], b, c, 0, 0, 0);
        }
        acc[nt] = c;
    }

    int lrow0 = wv * 16 + quad * 4;
#pragma unroll
    for (int nt = 0; nt < 8; ++nt) {
        int n = nt * 16 + m;
        float bias = b2[n];
#pragma unroll
        for (int r = 0; r < 4; ++r)
            tb[(lrow0 + r) * TPITCH + n] = f2bf(fmaxf(acc[nt][r] + bias, 0.f));
    }
    __syncthreads();
    int lrow = tid >> 2, off = (tid & 3) * 32;
    int grow = blockIdx.x * 64 + lrow;
    if (grow < N_NODES) {
#pragma unroll
        for (int i = 0; i < 4; ++i)
            *(short8*)(xout + (size_t)grow * HDIM + off + i * 8) =
                *(const short8*)&tb[lrow * TPITCH + off + i * 8];
    }
}

// ---------------- pool: g[gid] = sum of node rows (bf16 out) ----------------

__global__ __launch_bounds__(256) void k_pool(
    const unsigned short* __restrict__ xf,
    const int* __restrict__ batch,
    unsigned short* __restrict__ g)
{
    __shared__ float red[16][HDIM];
    int gid = blockIdx.x;
    int tid = threadIdx.x;

    int lo = 0, hi = N_NODES;
    while (lo < hi) { int mid = (lo + hi) >> 1; if (batch[mid] < gid) lo = mid + 1; else hi = mid; }
    int start = lo;
    int lo2 = start, hi2 = N_NODES;
    while (lo2 < hi2) { int mid = (lo2 + hi2) >> 1; if (batch[mid] < gid + 1) lo2 = mid + 1; else hi2 = mid; }
    int end = lo2;

    int tsub = tid & 15, rgrp = tid >> 4;
    int seg = tsub * 8;
    float acc[8] = {0.f, 0.f, 0.f, 0.f, 0.f, 0.f, 0.f, 0.f};
    for (int r = start + rgrp; r < end; r += 16) {
        short8 v = *(const short8*)(xf + (size_t)r * HDIM + seg);
#pragma unroll
        for (int j = 0; j < 8; ++j) acc[j] += bf2f((unsigned short)v[j]);
    }
#pragma unroll
    for (int j = 0; j < 8; ++j) red[rgrp][seg + j] = acc[j];
    __syncthreads();
    if (tid < HDIM) {
        float s = 0.f;
#pragma unroll
        for (int i = 0; i < 16; ++i) s += red[i][tid];
        g[gid * HDIM + tid] = f2bf(s);
    }
}

// ---------------- head: out = relu(g@hW1+b1) @ hW2 + b2 (block-local) -------

__global__ __launch_bounds__(256) void k_head(
    const unsigned short* __restrict__ g,
    const unsigned short* __restrict__ w1t,  // [128][128] bf16 [n][k]
    const float* __restrict__ b1,
    const unsigned short* __restrict__ w2t,  // [64][128] bf16 [n][k]
    const float* __restrict__ b2,
    float* __restrict__ out)
{
    __shared__ unsigned short tb[64 * HPITCH];
    int tid = threadIdx.x;
    int wv = tid >> 6, lane = tid & 63;
    int m = lane & 15, quad = lane >> 4;
    int row0 = blockIdx.x * 64 + wv * 16;

    short8 a[4];
#pragma unroll
    for (int kk = 0; kk < 4; ++kk)
        a[kk] = *(const short8*)(g + (size_t)(row0 + m) * HDIM + kk * 32 + quad * 8);

    // stage 1: t = relu(g @ W1 + b1), 64x128, staged to LDS
#pragma unroll
    for (int nt = 0; nt < 8; ++nt) {
        floatx4 c = {0.f, 0.f, 0.f, 0.f};
#pragma unroll
        for (int kk = 0; kk < 4; ++kk) {
            short8 b = *(const short8*)(w1t + (nt * 16 + m) * HDIM + kk * 32 + quad * 8);
            c = __builtin_amdgcn_mfma_f32_16x16x32_bf16(a[kk], b, c, 0, 0, 0);
        }
        int n = nt * 16 + m;
        float bias = b1[n];
#pragma unroll
        for (int r = 0; r < 4; ++r) {
            int lrow = wv * 16 + quad * 4 + r;
            tb[lrow * HPITCH + n] = f2bf(fmaxf(c[r] + bias, 0.f));
        }
    }
    __syncthreads();

    // stage 2: out = t @ W2 + b2, 64x64
    short8 a2[4];
#pragma unroll
    for (int kk = 0; kk < 4; ++kk)
        a2[kk] = *(const short8*)&tb[(wv * 16 + m) * HPITCH + kk * 32 + quad * 8];

#pragma unroll
    for (int nt = 0; nt < 4; ++nt) {
        floatx4 c = {0.f, 0.f, 0.f, 0.f};
#pragma unroll
        for (int kk = 0; kk < 4; ++kk) {
            short8 b = *(const short8*)(w2t + (nt * 16 + m) * HDIM + kk * 32 + quad * 8);
            c = __builtin_amdgcn_mfma_f32_16x16x32_bf16(a2[kk], b, c, 0, 0, 0);
        }
        int n = nt * 16 + m;
        float bias = b2[n];
#pragma unroll
        for (int r = 0; r < 4; ++r) {
            int row = row0 + quad * 4 + r;
            out[(size_t)row * ODIM + n] = c[r] + bias;
        }
    }
}

// ---------------- launch ----------------

extern "C" void kernel_launch(void* const* d_in, const int* in_sizes, int n_in,
                              void* d_out, int out_size, void* d_ws, size_t ws_size,
                              hipStream_t stream) {
    const float* x        = (const float*)d_in[0];
    const float* conv_W1  = (const float*)d_in[1];
    const float* conv_b1  = (const float*)d_in[2];
    const float* conv_g   = (const float*)d_in[3];
    const float* conv_be  = (const float*)d_in[4];
    const float* conv_W2  = (const float*)d_in[5];
    const float* conv_b2  = (const float*)d_in[6];
    const float* head_W1  = (const float*)d_in[7];
    const float* head_b1  = (const float*)d_in[8];
    const float* head_W2  = (const float*)d_in[9];
    const float* head_b2  = (const float*)d_in[10];
    const int*   edges    = (const int*)d_in[11];   // [0..E)=src, [E..2E)=dst
    const int*   batch    = (const int*)d_in[12];

    char* ws = (char*)d_ws;
    int*            cnt    = (int*)(ws + 0);                    // 200,000 B
    float*          stats  = (float*)(ws + 200000);             // 3*256*4 = 3,072 B
    unsigned short* colidx = (unsigned short*)(ws + 203072);    // 50000*48*2 = 4,800,000 B
    unsigned short* wtb    = (unsigned short*)(ws + 5003072);   // 245,760 B
    float*          part   = (float*)(ws + 5248832);            // 782*256*4 = 800,768 B
    unsigned short* gbuf   = (unsigned short*)(ws + 6049600);   // 131,072 B
    unsigned short* xa     = (unsigned short*)(ws + 6180672);   // (N+1) rows = 12,800,256 B
    unsigned short* xb     = (unsigned short*)(ws + 18980928);  // 12,800,256 B
    (void)in_sizes; (void)n_in; (void)out_size; (void)ws_size;

    hipMemsetAsync(ws, 0, 200000, stream);                      // cnt only

    k_prep<<<SCAT_BLK + CVT_BLK + CVTW_BLK, 256, 0, stream>>>(
        edges, edges + N_EDGES, cnt, colidx, x, xa,
        conv_W1, conv_W2, head_W1, head_W2, wtb, xb);
    k_pad<<<(N_NODES + 255) / 256, 256, 0, stream>>>(cnt, colidx);

    // x lives in xa for every layer; h in xb.
    for (int l = 0; l < NLAYER; ++l) {
        k_gml<<<GBLK, 512, 0, stream>>>(xa, cnt, colidx,
                                        wtb + (2 * l) * HDIM * HDIM,
                                        conv_b1 + l * HDIM, xb, part);
        k_stats<<<256, 256, 0, stream>>>(part, stats + l * 256);
        k_mlp2<<<NBLK, 256, 0, stream>>>(xb, stats + l * 256,
                                         conv_g + l * HDIM, conv_be + l * HDIM,
                                         wtb + (2 * l + 1) * HDIM * HDIM,
                                         conv_b2 + l * HDIM, xa);
    }

    k_pool<<<NGRAPH, 256, 0, stream>>>(xa, batch, gbuf);
    k_head<<<NGRAPH / 64, 256, 0, stream>>>(gbuf, wtb + 6 * HDIM * HDIM, head_b1,
                                            wtb + 7 * HDIM * HDIM, head_b2,
                                            (float*)d_out);
}